// Round 7
// baseline (645.176 us; speedup 1.0000x reference)
//
#include <hip/hip_runtime.h>
#include <math.h>

// DiscriminativeLoss: embeddings (8,16,512,512) f32, instance_masks (8,512,512) i32 in [0,33)
// out: 4 f32 [total, var, dist, reg]
//
// SINGLE fused kernel: phase1 (one-hot MFMA segment sums) -> per-image flag sync ->
// phase2 (weighted hinge, emb re-read is L3-warm) -> last-block final reduction.
// Co-residency guaranteed: __launch_bounds__(256,4) (<=128 VGPR) + 25KB LDS => 4 blocks/CU
// capacity = 1024 = grid. Spin is iteration-capped (fails loud, not hung).
// gsum layout: [B][32][17]  (cols 0..15 = channel sums, col 16 = count), segs 1..32.

#define B 8
#define E 16
#define HW (512*512)
#define BLK 256
#define P_BPI 128              // blocks per image
#define GRID (P_BPI * B)       // 1024 = exactly 4 blocks/CU * 256 CUs
#define PPW 512                // pixels per wave (phase1)
#define NTILES (PPW / 16)      // 32 MFMA K-tiles per wave
#define P2_VPB 512             // float4-groups per block (2048 px) = 2 iters/thread

typedef __attribute__((ext_vector_type(8)))  short short8;
typedef __attribute__((ext_vector_type(16))) float floatx16;

__device__ __forceinline__ float atomAddF(float* p, float v) {
  return unsafeAtomicAdd(p, v);
}

// pack trunc-bf16(a) | trunc-bf16(b)<<16 in ONE v_perm_b32
__device__ __forceinline__ unsigned pack_bf(float a, float b) {
  return __builtin_amdgcn_perm(__float_as_uint(b), __float_as_uint(a), 0x07060302u);
}

union Smem {
  struct { int4 mstage[4][128]; float lred[4][32][33]; } p1;   // 25.1 KB
  struct { float mean4[33][4][4]; float winv[33]; } p2;        // 2.3 KB
  struct { float mean[B][32][E]; float cnts[B][32]; } fin;     // 17.4 KB
};

__global__ __launch_bounds__(BLK, 4) void fused_kernel(
    const float* __restrict__ emb, const int* __restrict__ mask,
    float* __restrict__ gsum /*[B][32][17]*/, float* __restrict__ vsum /*[B]*/,
    int* __restrict__ flags /*[B]*/, int* __restrict__ done /*[1]*/,
    float* __restrict__ out) {
  __shared__ Smem sm;
  __shared__ float wred[4];
  __shared__ float rb[B], db[B], pb[B], nb[B];
  __shared__ int lastblk;

  const int blk   = blockIdx.x;
  const int b     = blk >> 7;          // image
  const int slice = blk & 127;         // slice within image
  const int t     = threadIdx.x;
  const int lane  = t & 63;
  const int wv    = __builtin_amdgcn_readfirstlane(t >> 6);

  // ================= PHASE 1: one-hot MFMA segment sums =================
  {
    const int n    = lane & 31;      // A row (segment id-1) / D col
    const int h    = lane >> 5;      // k-half
    const int myid = n + 1;
    const bool ld  = (n < 16);
    const int wbase = (slice * 4 + wv) * PPW;

    {  // stage this wave's 512 mask values into LDS (native int4: aligned b128)
      const int4* __restrict__ mg = (const int4*)(mask + (size_t)b * HW + wbase);
      sm.p1.mstage[wv][lane]      = mg[lane];
      sm.p1.mstage[wv][64 + lane] = mg[64 + lane];
    }
    __syncthreads();

    const float* __restrict__ pl = emb + ((size_t)b * E + (n & 15)) * HW + wbase + 8 * h;

    floatx16 acc;
#pragma unroll
    for (int i = 0; i < 16; ++i) acc[i] = 0.f;

    float4 fb[4][2];                 // 4-deep ring: tiles tl..tl+3 in flight
#pragma unroll
    for (int u = 0; u < 4; ++u) {
      if (ld) {
        fb[u][0] = ((const float4*)(pl + u * 16))[0];
        fb[u][1] = ((const float4*)(pl + u * 16))[1];
      }
    }

    for (int tl4 = 0; tl4 < NTILES; tl4 += 4) {
#pragma unroll
      for (int u = 0; u < 4; ++u) {
        const int tl = tl4 + u;
        const int4 A0 = sm.p1.mstage[wv][tl * 4 + 2 * h];
        const int4 A1 = sm.p1.mstage[wv][tl * 4 + 2 * h + 1];

        short8 af;
        af[0] = (A0.x == myid) ? (short)0x3F80 : (short)0;
        af[1] = (A0.y == myid) ? (short)0x3F80 : (short)0;
        af[2] = (A0.z == myid) ? (short)0x3F80 : (short)0;
        af[3] = (A0.w == myid) ? (short)0x3F80 : (short)0;
        af[4] = (A1.x == myid) ? (short)0x3F80 : (short)0;
        af[5] = (A1.y == myid) ? (short)0x3F80 : (short)0;
        af[6] = (A1.z == myid) ? (short)0x3F80 : (short)0;
        af[7] = (A1.w == myid) ? (short)0x3F80 : (short)0;

        short8 bf;
        if (ld) {
          union { uint4 u4; short8 s; } cv;
          cv.u4.x = pack_bf(fb[u][0].x, fb[u][0].y);
          cv.u4.y = pack_bf(fb[u][0].z, fb[u][0].w);
          cv.u4.z = pack_bf(fb[u][1].x, fb[u][1].y);
          cv.u4.w = pack_bf(fb[u][1].z, fb[u][1].w);
          bf = cv.s;
        } else if (n == 16) {
          const short one = (short)0x3F80;
          bf[0]=one; bf[1]=one; bf[2]=one; bf[3]=one; bf[4]=one; bf[5]=one; bf[6]=one; bf[7]=one;
        } else {
          bf[0]=0; bf[1]=0; bf[2]=0; bf[3]=0; bf[4]=0; bf[5]=0; bf[6]=0; bf[7]=0;
        }

        acc = __builtin_amdgcn_mfma_f32_32x32x16_bf16(af, bf, acc, 0, 0, 0);

        const int tn = tl + 4;       // refill slot u (constant index: no copy chain)
        if (tn < NTILES && ld) {
          fb[u][0] = ((const float4*)(pl + tn * 16))[0];
          fb[u][1] = ((const float4*)(pl + tn * 16))[1];
        }
      }
    }

    // C/D layout (m74/m101): col = lane&31, row = (reg&3)+8*(reg>>2)+4*(lane>>5)
#pragma unroll
    for (int r = 0; r < 16; ++r) {
      const int row = (r & 3) + 8 * (r >> 2) + 4 * h;
      sm.p1.lred[wv][row][n] = acc[r];
    }
    __syncthreads();

    for (int i = t; i < 32 * 32; i += BLK) {
      const int row = i >> 5, col = i & 31;
      if (col < 17) {
        const float s = sm.p1.lred[0][row][col] + sm.p1.lred[1][row][col]
                      + sm.p1.lred[2][row][col] + sm.p1.lred[3][row][col];
        atomAddF(&gsum[((size_t)b * 32 + row) * 17 + col], s);
      }
    }
  }

  // ---- signal: this block's image-b sums are published ----
  __threadfence();
  __syncthreads();
  if (t == 0)
    __hip_atomic_fetch_add(&flags[b], 1, __ATOMIC_RELEASE, __HIP_MEMORY_SCOPE_AGENT);

  // ---- wait: all 128 blocks of image b published (capped spin: no hangs) ----
  if (t == 0) {
    long it = 0;
    while (__hip_atomic_load(&flags[b], __ATOMIC_ACQUIRE, __HIP_MEMORY_SCOPE_AGENT) < P_BPI) {
      __builtin_amdgcn_s_sleep(8);
      if (++it > 200000000L) break;
    }
  }
  __syncthreads();
  __threadfence();

  // ================= PHASE 2: weighted hinge (emb re-read: L3-warm) =================
  {
    // Swizzle: chunk j of row k at slot (j+k+(k>>2))&3 -> all 8 bank-groups covered.
    for (int i = t; i < 33 * 16; i += BLK) {
      const int k = i >> 4, e = i & 15;
      float m = 0.f;
      if (k >= 1) {
        const float cnt = gsum[((size_t)b * 32 + (k - 1)) * 17 + 16];
        const float cc  = cnt > 1.f ? cnt : 1.f;
        m = gsum[((size_t)b * 32 + (k - 1)) * 17 + e] / cc;
      }
      const int j = e >> 2;
      sm.p2.mean4[k][(j + k + (k >> 2)) & 3][e & 3] = m;
    }
    if (t < 33) {
      float w = 0.f;
      if (t >= 1) {
        const float cnt = gsum[((size_t)b * 32 + (t - 1)) * 17 + 16];
        w = cnt > 0.5f ? 1.f / cnt : 0.f;
      }
      sm.p2.winv[t] = w;
    }
    __syncthreads();

    const int4*  __restrict__ maskv = (const int4*)(mask + (size_t)b * HW);
    const float* __restrict__ embb  = emb + (size_t)b * E * HW;
    const int v0 = slice * P2_VPB;
    float vacc = 0.f;

#pragma unroll 1
    for (int v = v0 + t; v < v0 + P2_VPB; v += BLK) {
      const int4 id = maskv[v];
      float4 x[E];
#pragma unroll
      for (int e = 0; e < E; ++e) x[e] = ((const float4*)(embb + (size_t)e * HW))[v];

      const int sx = id.x + (id.x >> 2);
      const int sy = id.y + (id.y >> 2);
      const int sz = id.z + (id.z >> 2);
      const int sw = id.w + (id.w >> 2);

      float d0 = 0.f, d1 = 0.f, d2 = 0.f, d3 = 0.f;
#pragma unroll
      for (int j = 0; j < 4; ++j) {
        const float4 m0 = *(const float4*)&sm.p2.mean4[id.x][(j + sx) & 3][0];
        const float4 m1 = *(const float4*)&sm.p2.mean4[id.y][(j + sy) & 3][0];
        const float4 m2 = *(const float4*)&sm.p2.mean4[id.z][(j + sz) & 3][0];
        const float4 m3 = *(const float4*)&sm.p2.mean4[id.w][(j + sw) & 3][0];
        const float4 a0 = x[4 * j + 0], a1 = x[4 * j + 1];
        const float4 a2 = x[4 * j + 2], a3 = x[4 * j + 3];
        float u;
        u = a0.x - m0.x; d0 += u * u;  u = a1.x - m0.y; d0 += u * u;
        u = a2.x - m0.z; d0 += u * u;  u = a3.x - m0.w; d0 += u * u;
        u = a0.y - m1.x; d1 += u * u;  u = a1.y - m1.y; d1 += u * u;
        u = a2.y - m1.z; d1 += u * u;  u = a3.y - m1.w; d1 += u * u;
        u = a0.z - m2.x; d2 += u * u;  u = a1.z - m2.y; d2 += u * u;
        u = a2.z - m2.z; d2 += u * u;  u = a3.z - m2.w; d2 += u * u;
        u = a0.w - m3.x; d3 += u * u;  u = a1.w - m3.y; d3 += u * u;
        u = a2.w - m3.z; d3 += u * u;  u = a3.w - m3.w; d3 += u * u;
      }
      float hh;  // weighted hinge -> register; winv[0]=0 kills background
      hh = fmaxf(sqrtf(d0) - 0.5f, 0.f); vacc += hh * hh * sm.p2.winv[id.x];
      hh = fmaxf(sqrtf(d1) - 0.5f, 0.f); vacc += hh * hh * sm.p2.winv[id.y];
      hh = fmaxf(sqrtf(d2) - 0.5f, 0.f); vacc += hh * hh * sm.p2.winv[id.z];
      hh = fmaxf(sqrtf(d3) - 0.5f, 0.f); vacc += hh * hh * sm.p2.winv[id.w];
    }

#pragma unroll
    for (int off = 32; off >= 1; off >>= 1) vacc += __shfl_down(vacc, off, 64);
    if ((t & 63) == 0) wred[t >> 6] = vacc;
    __syncthreads();
    if (t == 0) atomAddF(&vsum[b], wred[0] + wred[1] + wred[2] + wred[3]);
  }

  // ---- last block to finish runs the final reduction ----
  if (t == 0) {
    __threadfence();
    const int old = __hip_atomic_fetch_add(done, 1, __ATOMIC_ACQ_REL, __HIP_MEMORY_SCOPE_AGENT);
    lastblk = (old == GRID - 1) ? 1 : 0;
  }
  __syncthreads();
  if (!lastblk) return;
  __threadfence();

  // ================= FINAL (one block): dist/reg/var losses =================
  if (t < B) { rb[t] = 0.f; db[t] = 0.f; pb[t] = 0.f; nb[t] = 0.f; }
  {
    const int bb = t >> 5, k = t & 31;           // 256 threads = B*32
    const float c  = gsum[((size_t)bb * 32 + k) * 17 + 16];
    const float cc = c > 1.f ? c : 1.f;
    sm.fin.cnts[bb][k] = c;
#pragma unroll
    for (int e = 0; e < E; ++e)
      sm.fin.mean[bb][k][e] = gsum[((size_t)bb * 32 + k) * 17 + e] / cc;
  }
  __syncthreads();

  {
    const int bb = t >> 5, k = t & 31;
    const float c = sm.fin.cnts[bb][k];
    if (c > 0.5f) {
      atomAddF(&nb[bb], 1.f);
      float sq = 0.f;
#pragma unroll
      for (int e = 0; e < E; ++e) { const float m = sm.fin.mean[bb][k][e]; sq += m * m; }
      atomAddF(&rb[bb], sq > 0.f ? sqrtf(sq) : 0.f);
    }
  }
  __syncthreads();

  for (int idx = t; idx < B * 32 * 32; idx += BLK) {
    const int bb = idx >> 10;
    const int p  = idx & 1023;
    const int i  = p >> 5;
    const int j  = p & 31;
    if (i < j && sm.fin.cnts[bb][i] > 0.5f && sm.fin.cnts[bb][j] > 0.5f) {
      atomAddF(&pb[bb], 1.f);
      float sq = 0.f;
#pragma unroll
      for (int e = 0; e < E; ++e) {
        const float d = sm.fin.mean[bb][i][e] - sm.fin.mean[bb][j][e];
        sq += d * d;
      }
      const float dn = sq > 0.f ? sqrtf(sq) : 0.f;
      const float hh = 3.0f - dn;    // 2*DELTA_D - d
      if (hh > 0.f) atomAddF(&db[bb], hh * hh);
    }
  }
  __syncthreads();

  if (t == 0) {
    float sv = 0.f, sd = 0.f, sr = 0.f, svalid = 0.f;
    for (int bb = 0; bb < B; ++bb) {
      const float ni  = nb[bb];
      const float nim = ni > 1.f ? ni : 1.f;
      const float var_b = vsum[bb] / nim;
      const float reg_b = rb[bb] / nim;
      const float npm   = pb[bb] > 1.f ? pb[bb] : 1.f;
      const float dist_b = (ni > 1.f) ? (db[bb] / npm) : 0.f;
      const float valid  = ni > 0.f ? 1.f : 0.f;
      sv += var_b * valid;
      sd += dist_b * valid;
      sr += reg_b * valid;
      svalid += valid;
    }
    const float vs = svalid > 1.f ? svalid : 1.f;
    const float var = sv / vs, dist = sd / vs, reg = sr / vs;
    out[0] = var + dist + 0.001f * reg;
    out[1] = var;
    out[2] = dist;
    out[3] = reg;
  }
}

extern "C" void kernel_launch(void* const* d_in, const int* in_sizes, int n_in,
                              void* d_out, int out_size, void* d_ws, size_t ws_size,
                              hipStream_t stream) {
  const float* emb  = (const float*)d_in[0];
  const int*   mask = (const int*)d_in[1];
  float* out = (float*)d_out;

  float* gsum  = (float*)d_ws;                                     // B*32*17 = 4352 f
  float* vsum  = (float*)((char*)d_ws + (size_t)(B * 32 * 17) * 4);   // B f
  int*   flags = (int*)((char*)d_ws + (size_t)(B * 32 * 17 + B) * 4); // B i
  int*   done  = (int*)((char*)d_ws + (size_t)(B * 32 * 17 + 2 * B) * 4); // 1 i

  hipMemsetAsync(d_ws, 0, (size_t)(B * 32 * 17 + 2 * B + 1) * 4, stream);

  fused_kernel<<<GRID, BLK, 0, stream>>>(emb, mask, gsum, vsum, flags, done, out);
}